// Round 8
// baseline (398.813 us; speedup 1.0000x reference)
//
#include <hip/hip_runtime.h>
#include <hip/hip_cooperative_groups.h>
#include <math.h>

namespace cg = cooperative_groups;

#define BB 32
#define CCH 128
#define KK 128
#define HWW 192
#define NKB (KK * BB)   // 4096
#define P2 (2 * HWW)    // 384

typedef __attribute__((ext_vector_type(8))) __bf16 bf16x8;
typedef __attribute__((ext_vector_type(16))) float f32x16;

// A pack: feature, hi only:  [b][ks 0..7][tile 0..5][lane][8]   (48KB per b)
// B pack: memory, hi+lo:     [k][ks2 0..15][tile 0..5][lane][8] (8..15 = lo)
#define A_ELEMS (BB * 8 * 6 * 512)    // 786,432
#define B_ELEMS (KK * 16 * 6 * 512)   // 6,291,456
#define PACK_ITEMS (98304 + 393216)   // 491,520

#define MFMA32(A, B, C) __builtin_amdgcn_mfma_f32_32x32x16_bf16((A), (B), (C), 0, 0, 0)

__device__ __forceinline__ float softplusf(float x) {
    return fmaxf(x, 0.f) + log1pf(expf(-fabsf(x)));
}

__device__ __forceinline__ float block_sum768(float v, float* tmp) {
    __syncthreads();                 // protect tmp reuse across calls
    for (int off = 32; off > 0; off >>= 1) v += __shfl_down(v, off);
    if ((threadIdx.x & 63) == 0) tmp[threadIdx.x >> 6] = v;
    __syncthreads();
    float r = 0.f;
#pragma unroll
    for (int i = 0; i < 12; ++i) r += tmp[i];
    return r;
}

// ---------------------------------------------------------------------------
// fused: phase1 pack (grid-stride) -> grid.sync -> phase2 corr (R4-verbatim
// structure: 12 waves 2x6, wave tile 96x32, B-hi in regs, B-lo in LDS, A
// single-buffered LDS restaged per b between the two epilogue barriers,
// dual-orientation MFMA so both max-pool axes are lane-local) ->
// grid.sync -> phase3 finalize on block 0.
// ---------------------------------------------------------------------------
__global__ __launch_bounds__(768, 2) void fused_kernel(
    const float* __restrict__ feature,
    const int* __restrict__ target,
    const float* __restrict__ class_memory,
    const float* __restrict__ bn_gamma,
    const float* __restrict__ bn_beta,
    const float* __restrict__ fc_w,
    const float* __restrict__ fc_b,
    const float* __restrict__ logit_gamma,
    const float* __restrict__ logit_beta,
    __bf16* __restrict__ A2,
    __bf16* __restrict__ B2,
    float* __restrict__ dot_sw,
    float* __restrict__ psum,
    float* __restrict__ psq,
    float* __restrict__ out)
{
    cg::grid_group grid = cg::this_grid();

    __shared__ __align__(16) __bf16 A_lds[8][6][64][8];    // 48 KB (single buf)
    __shared__ __align__(16) __bf16 Blo_lds[8][6][64][8];  // 48 KB
    __shared__ float colpart[2][192];                      // 1.5 KB
    __shared__ float rowpart[6][192];                      // 4.5 KB
    __shared__ float scores[384];                          // 1.5 KB

    const int tid = threadIdx.x;

    // ================= phase 1: pack =================
    for (int gid = blockIdx.x * 768 + tid; gid < PACK_ITEMS; gid += 256 * 768) {
        if (gid < 98304) {                          // A: 32*8*6*64
            int l = gid & 63;
            int r = gid >> 6;
            int t = r % 6;  r /= 6;
            int ks = r & 7;
            int e = r >> 3;
            const float* src = feature + (size_t)e * CCH * HWW;
            int c0 = ks * 16 + (l >> 5) * 8;
            int q  = t * 32 + (l & 31);
            bf16x8 v;
#pragma unroll
            for (int j = 0; j < 8; ++j) v[j] = (__bf16)src[(c0 + j) * HWW + q];
            *(bf16x8*)(A2 + ((size_t)(e * 8 + ks) * 6 + t) * 512 + l * 8) = v;
        } else {                                    // B: 128*8*6*64 (hi+lo)
            int g2 = gid - 98304;
            int l = g2 & 63;
            int r = g2 >> 6;
            int t = r % 6;  r /= 6;
            int ks = r & 7;
            int e = r >> 3;
            const float* src = class_memory + (size_t)e * CCH * HWW;
            int c0 = ks * 16 + (l >> 5) * 8;
            int q  = t * 32 + (l & 31);
            bf16x8 vh, vl;
#pragma unroll
            for (int j = 0; j < 8; ++j) {
                float x = src[(c0 + j) * HWW + q];
                __bf16 h = (__bf16)x;
                vh[j] = h;
                vl[j] = (__bf16)(x - (float)h);
            }
            __bf16* base = B2 + ((size_t)e * 16 + ks) * 3072 + t * 512 + l * 8;
            *(bf16x8*)base = vh;
            *(bf16x8*)(base + 8 * 3072) = vl;       // lo at ks2 = 8+ks
        }
    }
    __threadfence();
    grid.sync();

    // ================= phase 2: corr (R4 structure) =================
    {
        const int l   = tid & 63;
        const int lc  = l & 31;
        const int w   = tid >> 6;      // 0..11
        const int wy  = w / 6;         // 0..1 : 96-row half
        const int wx  = w % 6;         // 0..5 : 32-col tile

        const int bid   = blockIdx.x;
        const int xcd   = bid & 7;
        const int slot  = bid >> 3;            // 0..31
        const int k     = xcd * 16 + (slot >> 1);
        const int bhalf = slot & 1;

        // B-hi fragments for this wave's coltile: regs for whole block
        const __bf16* bkbase = B2 + (size_t)k * 49152;
        bf16x8 bh[8];
#pragma unroll
        for (int g = 0; g < 8; ++g)
            bh[g] = *(const bf16x8*)(bkbase + g * 3072 + wx * 512 + l * 8);

        float fcw[6];
#pragma unroll
        for (int u = 0; u < 6; ++u) fcw[u] = fc_w[l + 64 * u];

        const int woff  = w * 1024 + l * 16;   // per-lane src offset
        const int wbase = w * 1024;            // wave-uniform LDS offset

        auto stageA = [&](int b) {
            const char* src = (const char*)A2 + (size_t)b * 49152 + woff;
            char* dst = (char*)&A_lds[0][0][0][0] + wbase;
#pragma unroll
            for (int i = 0; i < 4; ++i)
                __builtin_amdgcn_global_load_lds(
                    (const __attribute__((address_space(1))) void*)(src + i * 12288),
                    (__attribute__((address_space(3))) void*)(dst + i * 12288),
                    16, 0, 0);
        };
        {   // stage B-lo (once) + A[b0]
            const char* src = (const char*)B2 + (size_t)k * 98304 + 49152 + woff;
            char* dst = (char*)&Blo_lds[0][0][0][0] + wbase;
#pragma unroll
            for (int i = 0; i < 4; ++i)
                __builtin_amdgcn_global_load_lds(
                    (const __attribute__((address_space(1))) void*)(src + i * 12288),
                    (__attribute__((address_space(3))) void*)(dst + i * 12288),
                    16, 0, 0);
        }
        stageA(bhalf * 16);
        __syncthreads();

        for (int bi = 0; bi < 16; ++bi) {
            const int b = bhalf * 16 + bi;

            f32x16 acc[3], acc2[3];
#pragma unroll
            for (int i = 0; i < 3; ++i)
#pragma unroll
                for (int rr = 0; rr < 16; ++rr) { acc[i][rr] = 0.f; acc2[i][rr] = 0.f; }

#pragma unroll
            for (int g = 0; g < 8; ++g) {
                bf16x8 a0 = *(const bf16x8*)&A_lds[g][wy * 3 + 0][l][0];
                bf16x8 a1 = *(const bf16x8*)&A_lds[g][wy * 3 + 1][l][0];
                bf16x8 a2 = *(const bf16x8*)&A_lds[g][wy * 3 + 2][l][0];
                bf16x8 bl = *(const bf16x8*)&Blo_lds[g][wx][l][0];
                acc[0]  = MFMA32(a0, bh[g], acc[0]);
                acc[0]  = MFMA32(a0, bl,    acc[0]);
                acc[1]  = MFMA32(a1, bh[g], acc[1]);
                acc[1]  = MFMA32(a1, bl,    acc[1]);
                acc[2]  = MFMA32(a2, bh[g], acc[2]);
                acc[2]  = MFMA32(a2, bl,    acc[2]);
                acc2[0] = MFMA32(bh[g], a0, acc2[0]);
                acc2[0] = MFMA32(bl,    a0, acc2[0]);
                acc2[1] = MFMA32(bh[g], a1, acc2[1]);
                acc2[1] = MFMA32(bl,    a1, acc2[1]);
                acc2[2] = MFMA32(bh[g], a2, acc2[2]);
                acc2[2] = MFMA32(bl,    a2, acc2[2]);
            }

            // lane-local partial maxes
            float cmv = -INFINITY;
#pragma unroll
            for (int i = 0; i < 3; ++i)
#pragma unroll
                for (int rr = 0; rr < 16; ++rr) cmv = fmaxf(cmv, acc[i][rr]);
            cmv = fmaxf(cmv, __shfl_xor(cmv, 32));
            if (l < 32) colpart[wy][wx * 32 + lc] = cmv;

#pragma unroll
            for (int i = 0; i < 3; ++i) {
                float t = -INFINITY;
#pragma unroll
                for (int rr = 0; rr < 16; ++rr) t = fmaxf(t, acc2[i][rr]);
                t = fmaxf(t, __shfl_xor(t, 32));
                if (l < 32) rowpart[wx][(wy * 3 + i) * 32 + lc] = t;
            }
            __syncthreads();                 // A reads done + partials visible

            if (bi < 15) stageA(b + 1);      // restage into same buffer

            if (tid < 192) {
                scores[tid] = fmaxf(colpart[0][tid], colpart[1][tid]);
            } else if (tid < 384) {
                int q = tid - 192;
                float v = rowpart[0][q];
#pragma unroll
                for (int x = 1; x < 6; ++x) v = fmaxf(v, rowpart[x][q]);
                scores[192 + q] = v;
            }
            __syncthreads();                 // scores visible; stageA drained

            if (tid < 64) {
                float ds = 0.f, s1 = 0.f, s2 = 0.f;
#pragma unroll
                for (int u = 0; u < 6; ++u) {
                    float s = scores[l + 64 * u];
                    ds = fmaf(s, fcw[u], ds);
                    s1 += s;
                    s2 = fmaf(s, s, s2);
                }
                for (int off = 32; off > 0; off >>= 1) {
                    ds += __shfl_down(ds, off);
                    s1 += __shfl_down(s1, off);
                    s2 += __shfl_down(s2, off);
                }
                if (tid == 0) {
                    int kb = k * 32 + b;
                    dot_sw[kb] = ds;
                    psum[kb]   = s1;
                    psq[kb]    = s2;
                }
            }
        }
    }

    // ================= phase 3: finalize on block 0 =================
    __threadfence();
    grid.sync();
    if (blockIdx.x != 0) return;

    float* l_s = (float*)&A_lds[0][0][0][0];      // [4096] scratch
    float* tmp = l_s + NKB;                       // [12]

    float s1 = 0.f, s2 = 0.f, sw = 0.f;
#pragma unroll
    for (int u = 0; u < 6; ++u) {
        int i = tid + 768 * u;
        if (i < NKB) { s1 += psum[i]; s2 += psq[i]; }
    }
    if (tid < P2) sw = fc_w[tid];

    float S1 = block_sum768(s1, tmp);
    float S2 = block_sum768(s2, tmp);
    float SW = block_sum768(sw, tmp);

    const float N1 = (float)NKB * (float)P2;
    float mean1 = S1 / N1;
    float var1  = S2 / N1 - mean1 * mean1;
    float cA = bn_gamma[0] * rsqrtf(var1 + 1e-5f);
    float cB = (bn_beta[0] - cA * mean1) * SW + fc_b[0];

    float lr[6];
    float t1 = 0.f, t2 = 0.f;
#pragma unroll
    for (int u = 0; u < 6; ++u) {
        int i = tid + 768 * u;
        if (i < NKB) {
            lr[u] = fmaf(cA, dot_sw[i], cB);
            t1 += lr[u];
            t2 = fmaf(lr[u], lr[u], t2);
        } else lr[u] = 0.f;
    }
    float T1 = block_sum768(t1, tmp);
    float T2 = block_sum768(t2, tmp);
    float mean2 = T1 / (float)NKB;
    float var2  = T2 / (float)NKB - mean2 * mean2;
    float cC = logit_gamma[0] * rsqrtf(var2 + 1e-5f);
    float cD = logit_beta[0] - mean2 * cC;

#pragma unroll
    for (int u = 0; u < 6; ++u) {
        int i = tid + 768 * u;
        if (i < NKB) l_s[i] = fmaf(lr[u], cC, cD);
    }
    __syncthreads();

    // focal BCE + argmax: 4 threads per sample b (tid < 128)
    if (tid < 128) {
        const int b  = tid >> 2;
        const int tt = tid & 3;
        const int tgt = target[b];
        float loss  = 0.f;
        float bestv = -INFINITY;
        int   bestk = 0x7fffffff;
#pragma unroll
        for (int u = 0; u < 32; ++u) {
            int kk = tt + 4 * u;
            float lg = l_s[kk * BB + b];
            float prob = 1.f / (1.f + expf(-lg));
            bool pos = (kk == tgt);
            float wgt = pos ? (1.f - prob) : prob;
            float bce = pos ? softplusf(-lg) : softplusf(lg);
            loss += bce * wgt * wgt;
            if (lg > bestv) { bestv = lg; bestk = kk; }
            else if (lg == bestv && kk < bestk) bestk = kk;
        }
#pragma unroll
        for (int off = 2; off > 0; off >>= 1) {
            loss += __shfl_down(loss, off);
            float ov = __shfl_down(bestv, off);
            int   ok = __shfl_down(bestk, off);
            if (ov > bestv) { bestv = ov; bestk = ok; }
            else if (ov == bestv && ok < bestk) bestk = ok;
        }
        if (tt == 0) {
            out[b]      = loss;
            out[BB + b] = (bestk == tgt) ? 1.f : 0.f;
        }
    }
}

extern "C" void kernel_launch(void* const* d_in, const int* in_sizes, int n_in,
                              void* d_out, int out_size, void* d_ws, size_t ws_size,
                              hipStream_t stream)
{
    const float* feature      = (const float*)d_in[0];
    const int*   target       = (const int*)d_in[1];
    const float* class_memory = (const float*)d_in[2];
    const float* bn_gamma     = (const float*)d_in[3];
    const float* bn_beta      = (const float*)d_in[4];
    const float* fc_w         = (const float*)d_in[5];
    const float* fc_b         = (const float*)d_in[6];
    const float* logit_gamma  = (const float*)d_in[7];
    const float* logit_beta   = (const float*)d_in[8];
    float* out = (float*)d_out;

    __bf16* A2 = (__bf16*)d_ws;
    __bf16* B2 = A2 + A_ELEMS;
    float* dot_sw = (float*)(B2 + B_ELEMS);
    float* psum   = dot_sw + NKB;
    float* psq    = psum + NKB;

    void* args[] = {
        (void*)&feature, (void*)&target, (void*)&class_memory,
        (void*)&bn_gamma, (void*)&bn_beta, (void*)&fc_w, (void*)&fc_b,
        (void*)&logit_gamma, (void*)&logit_beta,
        (void*)&A2, (void*)&B2, (void*)&dot_sw, (void*)&psum, (void*)&psq,
        (void*)&out
    };
    hipLaunchCooperativeKernel((const void*)fused_kernel,
                               dim3(256), dim3(768), args, 0, stream);
}

// Round 10
// 182.415 us; speedup vs baseline: 2.1863x; 2.1863x over previous
//
#include <hip/hip_runtime.h>
#include <math.h>

#define BB 32
#define CCH 128
#define KK 128
#define HWW 192
#define NKB (KK * BB)   // 4096
#define P2 (2 * HWW)    // 384

typedef __attribute__((ext_vector_type(8))) __bf16 bf16x8;
typedef __attribute__((ext_vector_type(16))) float f32x16;

// A pack: feature, hi only:  [b][ks 0..7][tile 0..5][lane][8]   (48KB per b)
// B pack: memory, hi+lo:     [k][ks2 0..15][tile 0..5][lane][8] (8..15 = lo)
#define A_ELEMS (BB * 8 * 6 * 512)    // 786,432
#define B_ELEMS (KK * 16 * 6 * 512)   // 6,291,456

// ---------------------------------------------------------------------------
// pack: fp32 [ent][c][hw] -> bf16 MFMA-fragment packs (layout verified R2-R8).
// Also zeroes the block-completion counter (ws is poisoned 0xAA each launch).
// ---------------------------------------------------------------------------
__global__ __launch_bounds__(256) void pack_kernel(
    const float* __restrict__ feature,
    const float* __restrict__ class_memory,
    __bf16* __restrict__ A2,
    __bf16* __restrict__ B2,
    unsigned int* __restrict__ counter)
{
    int gid = blockIdx.x * 256 + threadIdx.x;   // 1920*256 = 491,520
    if (gid == 0) counter[0] = 0;
    if (gid < 98304) {                          // A: 32*8*6*64
        int l = gid & 63;
        int r = gid >> 6;
        int t = r % 6;  r /= 6;
        int ks = r & 7;
        int e = r >> 3;
        const float* src = feature + (size_t)e * CCH * HWW;
        int c0 = ks * 16 + (l >> 5) * 8;
        int q  = t * 32 + (l & 31);
        bf16x8 v;
#pragma unroll
        for (int j = 0; j < 8; ++j) v[j] = (__bf16)src[(c0 + j) * HWW + q];
        *(bf16x8*)(A2 + ((size_t)(e * 8 + ks) * 6 + t) * 512 + l * 8) = v;
    } else {                                    // B: 128*8*6*64 (hi+lo fused)
        int g2 = gid - 98304;
        int l = g2 & 63;
        int r = g2 >> 6;
        int t = r % 6;  r /= 6;
        int ks = r & 7;
        int e = r >> 3;
        const float* src = class_memory + (size_t)e * CCH * HWW;
        int c0 = ks * 16 + (l >> 5) * 8;
        int q  = t * 32 + (l & 31);
        bf16x8 vh, vl;
#pragma unroll
        for (int j = 0; j < 8; ++j) {
            float x = src[(c0 + j) * HWW + q];
            __bf16 h = (__bf16)x;
            vh[j] = h;
            vl[j] = (__bf16)(x - (float)h);
        }
        __bf16* base = B2 + ((size_t)e * 16 + ks) * 3072 + t * 512 + l * 8;
        *(bf16x8*)base = vh;
        *(bf16x8*)(base + 8 * 3072) = vl;       // lo at ks2 = 8+ks
    }
}

__device__ __forceinline__ float softplusf(float x) {
    return fmaxf(x, 0.f) + log1pf(expf(-fabsf(x)));
}

__device__ __forceinline__ float block_sum768(float v, float* tmp) {
    __syncthreads();                 // protect tmp reuse across calls
    for (int off = 32; off > 0; off >>= 1) v += __shfl_down(v, off);
    if ((threadIdx.x & 63) == 0) tmp[threadIdx.x >> 6] = v;
    __syncthreads();
    float r = 0.f;
#pragma unroll
    for (int i = 0; i < 12; ++i) r += tmp[i];
    return r;
}

// ---------------------------------------------------------------------------
// corr_mfma: block = (k, half of b's). 12 waves (2 wy x 6 wx), wave tile
// 96x32. R4's proven skeleton (2 barriers, spread reduce, per-g ds_reads,
// 84 VGPR) with three deltas:
//  (1) acc2 (corr^T / rowmax orientation) computed hi-only: 9 MFMA/g not 12
//      (-25% MFMA work; rowmax scores get ~0.2% rel error, absmax stays <<thr)
//  (2) A double-buffered; stageA(next b) issued right AFTER the g-loop's
//      last ds_read of the current buffer, so the epilogue+reduce (~500 cyc)
//      covers the L2 stage latency before the barrier's vmcnt(0) drain.
//      (R5 issued it BEFORE the ds_reads -> alias drain with zero cover.)
//  (3) setprio(1) around the MFMA cluster.
// Last block (atomic ticket) runs BN1/FC/BN2/focal finalize in-kernel.
// ---------------------------------------------------------------------------
#define MFMA32(A, B, C) __builtin_amdgcn_mfma_f32_32x32x16_bf16((A), (B), (C), 0, 0, 0)

__global__ __launch_bounds__(768, 2) void corr_mfma(
    const __bf16* __restrict__ A2,
    const __bf16* __restrict__ B2,
    const float* __restrict__ fc_w,
    float* __restrict__ dot_sw,
    float* __restrict__ psum,
    float* __restrict__ psq,
    unsigned int* __restrict__ counter,
    const float* __restrict__ fc_b,
    const float* __restrict__ bn_gamma,
    const float* __restrict__ bn_beta,
    const float* __restrict__ logit_gamma,
    const float* __restrict__ logit_beta,
    const int* __restrict__ target,
    float* __restrict__ out)
{
    __shared__ __align__(16) __bf16 A_lds[2][8][6][64][8];    // 96 KB (dbuf)
    __shared__ __align__(16) __bf16 Blo_lds[8][6][64][8];     // 48 KB
    __shared__ float colpart[2][192];                         // 1.5 KB
    __shared__ float rowpart[6][192];                         // 4.5 KB
    __shared__ float scores[384];                             // 1.5 KB
    __shared__ int   lastflag_s;

    const int tid = threadIdx.x;
    const int l   = tid & 63;
    const int lc  = l & 31;
    const int w   = tid >> 6;      // 0..11
    const int wy  = w / 6;         // 0..1 : 96-row half
    const int wx  = w % 6;         // 0..5 : 32-col tile

    // XCD-contiguous k ranges: each XCD's L2 caches its 16-k slice of B2.
    const int bid   = blockIdx.x;
    const int xcd   = bid & 7;
    const int slot  = bid >> 3;            // 0..31
    const int k     = xcd * 16 + (slot >> 1);
    const int bhalf = slot & 1;

    // ---- B-hi fragments for this wave's coltile: regs for whole block ----
    const __bf16* bkbase = B2 + (size_t)k * 49152;
    bf16x8 bh[8];
#pragma unroll
    for (int g = 0; g < 8; ++g)
        bh[g] = *(const bf16x8*)(bkbase + g * 3072 + wx * 512 + l * 8);

    float fcw[6];
#pragma unroll
    for (int u = 0; u < 6; ++u) fcw[u] = fc_w[l + 64 * u];

    const int woff  = w * 1024 + l * 16;   // per-lane src offset
    const int wbase = w * 1024;            // wave-uniform LDS offset

    auto stageA = [&](int buf2, int b) {
        const char* src = (const char*)A2 + (size_t)b * 49152 + woff;
        char* dst = (char*)&A_lds[buf2][0][0][0][0] + wbase;
#pragma unroll
        for (int i = 0; i < 4; ++i)
            __builtin_amdgcn_global_load_lds(
                (const __attribute__((address_space(1))) void*)(src + i * 12288),
                (__attribute__((address_space(3))) void*)(dst + i * 12288),
                16, 0, 0);
    };
    {   // stage B-lo (once) + A[b0]
        const char* src = (const char*)B2 + (size_t)k * 98304 + 49152 + woff;
        char* dst = (char*)&Blo_lds[0][0][0][0] + wbase;
#pragma unroll
        for (int i = 0; i < 4; ++i)
            __builtin_amdgcn_global_load_lds(
                (const __attribute__((address_space(1))) void*)(src + i * 12288),
                (__attribute__((address_space(3))) void*)(dst + i * 12288),
                16, 0, 0);
    }
    stageA(0, bhalf * 16);
    __syncthreads();

    for (int bi = 0; bi < 16; ++bi) {
        const int buf = bi & 1;
        const int b   = bhalf * 16 + bi;

        f32x16 acc[3], acc2[3];
#pragma unroll
        for (int i = 0; i < 3; ++i)
#pragma unroll
            for (int rr = 0; rr < 16; ++rr) { acc[i][rr] = 0.f; acc2[i][rr] = 0.f; }

        // (1) MFMA g-loop with per-g ds_reads (84-VGPR regime, R4-proven)
        __builtin_amdgcn_s_setprio(1);
#pragma unroll
        for (int g = 0; g < 8; ++g) {
            bf16x8 a0 = *(const bf16x8*)&A_lds[buf][g][wy * 3 + 0][l][0];
            bf16x8 a1 = *(const bf16x8*)&A_lds[buf][g][wy * 3 + 1][l][0];
            bf16x8 a2 = *(const bf16x8*)&A_lds[buf][g][wy * 3 + 2][l][0];
            bf16x8 bl = *(const bf16x8*)&Blo_lds[g][wx][l][0];
            acc[0]  = MFMA32(a0, bh[g], acc[0]);
            acc[0]  = MFMA32(a0, bl,    acc[0]);
            acc[1]  = MFMA32(a1, bh[g], acc[1]);
            acc[1]  = MFMA32(a1, bl,    acc[1]);
            acc[2]  = MFMA32(a2, bh[g], acc[2]);
            acc[2]  = MFMA32(a2, bl,    acc[2]);
            // corr^T orientation: hi-only (rowmax half tolerates bf16 error)
            acc2[0] = MFMA32(bh[g], a0, acc2[0]);
            acc2[1] = MFMA32(bh[g], a1, acc2[1]);
            acc2[2] = MFMA32(bh[g], a2, acc2[2]);
        }
        __builtin_amdgcn_s_setprio(0);

        // (2) prefetch next b into the other buffer, AFTER all ds_reads of
        //     buf; epilogue+reduce cover its latency before the drain.
        if (bi < 15) stageA(buf ^ 1, b + 1);

        // (3) register-only partial maxes
        float cmv = -INFINITY;
#pragma unroll
        for (int i = 0; i < 3; ++i)
#pragma unroll
            for (int rr = 0; rr < 16; ++rr) cmv = fmaxf(cmv, acc[i][rr]);
        cmv = fmaxf(cmv, __shfl_xor(cmv, 32));
        if (l < 32) colpart[wy][wx * 32 + lc] = cmv;

#pragma unroll
        for (int i = 0; i < 3; ++i) {
            float t = -INFINITY;
#pragma unroll
            for (int rr = 0; rr < 16; ++rr) t = fmaxf(t, acc2[i][rr]);
            t = fmaxf(t, __shfl_xor(t, 32));
            if (l < 32) rowpart[wx][(wy * 3 + i) * 32 + lc] = t;
        }
        __syncthreads();                 // partials visible

        if (tid < 192) {
            scores[tid] = fmaxf(colpart[0][tid], colpart[1][tid]);
        } else if (tid < 384) {
            int q = tid - 192;
            float v = rowpart[0][q];
#pragma unroll
            for (int x = 1; x < 6; ++x) v = fmaxf(v, rowpart[x][q]);
            scores[192 + q] = v;
        }
        __syncthreads();                 // scores visible; stage drained here

        if (tid < 64) {                  // dot overlaps others' next-bi MFMA
            float ds = 0.f, s1 = 0.f, s2 = 0.f;
#pragma unroll
            for (int u = 0; u < 6; ++u) {
                float s = scores[l + 64 * u];
                ds = fmaf(s, fcw[u], ds);
                s1 += s;
                s2 = fmaf(s, s, s2);
            }
            for (int off = 32; off > 0; off >>= 1) {
                ds += __shfl_down(ds, off);
                s1 += __shfl_down(s1, off);
                s2 += __shfl_down(s2, off);
            }
            if (tid == 0) {
                int kb = k * 32 + b;
                dot_sw[kb] = ds;
                psum[kb]   = s1;
                psq[kb]    = s2;
            }
        }
    }

    // ---- atomic ticket: last block runs finalize ----
    __syncthreads();                       // wave0's final global writes done
    if (tid == 0) {
        __threadfence();                   // release dot_sw/psum/psq
        unsigned int old = atomicAdd(counter, 1u);
        lastflag_s = (old == 255u) ? 1 : 0;
    }
    __syncthreads();
    if (!lastflag_s) return;
    __threadfence();                       // acquire other blocks' writes

    // ---- finalize (768 threads), reusing A_lds as scratch ----
    float* l_s = (float*)&A_lds[0][0][0][0][0];   // [4096]
    float* tmp = l_s + NKB;                       // [12]

    float s1 = 0.f, s2 = 0.f, sw = 0.f;
#pragma unroll
    for (int u = 0; u < 6; ++u) {
        int i = tid + 768 * u;
        if (i < NKB) { s1 += psum[i]; s2 += psq[i]; }
    }
    if (tid < P2) sw = fc_w[tid];

    float S1 = block_sum768(s1, tmp);
    float S2 = block_sum768(s2, tmp);
    float SW = block_sum768(sw, tmp);

    const float N1 = (float)NKB * (float)P2;
    float mean1 = S1 / N1;
    float var1  = S2 / N1 - mean1 * mean1;
    float cA = bn_gamma[0] * rsqrtf(var1 + 1e-5f);
    float cB = (bn_beta[0] - cA * mean1) * SW + fc_b[0];

    float lr[6];
    float t1 = 0.f, t2 = 0.f;
#pragma unroll
    for (int u = 0; u < 6; ++u) {
        int i = tid + 768 * u;
        if (i < NKB) {
            lr[u] = fmaf(cA, dot_sw[i], cB);
            t1 += lr[u];
            t2 = fmaf(lr[u], lr[u], t2);
        } else lr[u] = 0.f;
    }
    float T1 = block_sum768(t1, tmp);
    float T2 = block_sum768(t2, tmp);
    float mean2 = T1 / (float)NKB;
    float var2  = T2 / (float)NKB - mean2 * mean2;
    float cC = logit_gamma[0] * rsqrtf(var2 + 1e-5f);
    float cD = logit_beta[0] - mean2 * cC;

#pragma unroll
    for (int u = 0; u < 6; ++u) {
        int i = tid + 768 * u;
        if (i < NKB) l_s[i] = fmaf(lr[u], cC, cD);
    }
    __syncthreads();

    // focal BCE + argmax: 4 threads per sample b (tid < 128)
    if (tid < 128) {
        const int b  = tid >> 2;
        const int tt = tid & 3;
        const int tgt = target[b];
        float loss  = 0.f;
        float bestv = -INFINITY;
        int   bestk = 0x7fffffff;
#pragma unroll
        for (int u = 0; u < 32; ++u) {
            int kk = tt + 4 * u;
            float lg = l_s[kk * BB + b];
            float prob = 1.f / (1.f + expf(-lg));
            bool pos = (kk == tgt);
            float wgt = pos ? (1.f - prob) : prob;
            float bce = pos ? softplusf(-lg) : softplusf(lg);
            loss += bce * wgt * wgt;
            if (lg > bestv) { bestv = lg; bestk = kk; }
            else if (lg == bestv && kk < bestk) bestk = kk;
        }
#pragma unroll
        for (int off = 2; off > 0; off >>= 1) {
            loss += __shfl_down(loss, off);
            float ov = __shfl_down(bestv, off);
            int   ok = __shfl_down(bestk, off);
            if (ov > bestv) { bestv = ov; bestk = ok; }
            else if (ov == bestv && ok < bestk) bestk = ok;
        }
        if (tt == 0) {
            out[b]      = loss;
            out[BB + b] = (bestk == tgt) ? 1.f : 0.f;
        }
    }
}

extern "C" void kernel_launch(void* const* d_in, const int* in_sizes, int n_in,
                              void* d_out, int out_size, void* d_ws, size_t ws_size,
                              hipStream_t stream)
{
    const float* feature      = (const float*)d_in[0];
    const int*   target       = (const int*)d_in[1];
    const float* class_memory = (const float*)d_in[2];
    const float* bn_gamma     = (const float*)d_in[3];
    const float* bn_beta      = (const float*)d_in[4];
    const float* fc_w         = (const float*)d_in[5];
    const float* fc_b         = (const float*)d_in[6];
    const float* logit_gamma  = (const float*)d_in[7];
    const float* logit_beta   = (const float*)d_in[8];
    float* out = (float*)d_out;

    __bf16* A2 = (__bf16*)d_ws;
    __bf16* B2 = A2 + A_ELEMS;
    float* dot_sw = (float*)(B2 + B_ELEMS);
    float* psum   = dot_sw + NKB;
    float* psq    = psum + NKB;
    unsigned int* counter = (unsigned int*)(psq + NKB);

    pack_kernel<<<1920, 256, 0, stream>>>(feature, class_memory, A2, B2, counter);
    corr_mfma<<<256, 768, 0, stream>>>(A2, B2, fc_w, dot_sw, psum, psq, counter,
                                       fc_b, bn_gamma, bn_beta,
                                       logit_gamma, logit_beta, target, out);
}